// Round 6
// baseline (561.950 us; speedup 1.0000x reference)
//
#include <hip/hip_runtime.h>

#define NN 100000
#define NE 1600000
#define IN_DIM 512
#define HID 32
#define BN_EPS 1e-5f

#define E_PER 4           // edges cached in registers per thread (fill role)
#define FILL_BLOCKS 1600  // 1600*256*4 = 1.6384M >= NE
#define GEMM_BLOCKS 782   // 782*128 = 100096 >= NN rows
#define FG_BLOCKS (FILL_BLOCKS + GEMM_BLOCKS)
#define NSP 13            // src buckets of 8192 nodes (100000>>13 = 12 max)
#define NDP 25            // dst ranges of 4096 nodes (write-locality, R2 lesson)
#define NKP (NSP * NDP)   // 325 combined passes, src-major dst-minor
#define SEG 64            // fixed CSR slots per node; deg ~ Poisson(16), P(>=64) ~ 1e-19

// ---------------- utility ----------------
__global__ void k_zero(int* __restrict__ p, int n) {
    int i = blockIdx.x * 256 + threadIdx.x;
    if (i < n) p[i] = 0;
}

__device__ inline void fma4(float4& a, float s, const float4& w) {
    a.x = fmaf(s, w.x, a.x);
    a.y = fmaf(s, w.y, a.y);
    a.z = fmaf(s, w.z, a.z);
    a.w = fmaf(s, w.w, a.w);
}

// ---------------- fused CSR-fill + GEMM1 ----------------
// R2: fill (atomic/latency-bound) and gemm (HBM-BW-bound) are data-independent;
// block-interleaved 2:1 so both populations co-resident, stalls overlap.
// R4: fill passes keyed (src-bucket major, dst-range minor). Appends to each
// dst list arrive in src-bucket order (waves ~in sync across passes), so CSR
// lists come out approximately src-sorted at 8192 granularity. The agg
// kernels' gathers then cluster in a sliding ~1 MB window -> own-XCD L2 hits
// instead of L3 (R3 post-mortem: aggs are random-gather-BW-bound at 1.5 TB/s).
// dst-minor keeps the csr store window ~1 MB/pass (writeback amplification).
#define XS_S 132
__global__ __launch_bounds__(256) void k_fill_gemm(const int* __restrict__ src,
                                                   const int* __restrict__ dst,
                                                   int* __restrict__ cnt,
                                                   int* __restrict__ csr,
                                                   const float* __restrict__ x,
                                                   const float* __restrict__ W,
                                                   float* __restrict__ h) {
    __shared__ float XsT[32 * XS_S];  // 16.9 KB (gemm role only)
    __shared__ float Ws[32 * 32];     // 4 KB
    int bid = blockIdx.x;
    int t = threadIdx.x;
    bool is_gemm = (bid % 3 == 2) && (bid / 3 < GEMM_BLOCKS);

    if (!is_gemm) {
        // ---- fill role ----
        int f = bid - min(GEMM_BLOCKS, (bid + 1) / 3);
        const int nthreads = FILL_BLOCKS * 256;
        int tid = f * 256 + t;
        int s[E_PER], d[E_PER], key[E_PER];
#pragma unroll
        for (int k = 0; k < E_PER; k++) {
            int e = tid + k * nthreads;
            bool ok = (e < NE);
            s[k] = ok ? src[e] : 0;
            d[k] = ok ? dst[e] : 0;
            key[k] = ok ? ((s[k] >> 13) * NDP + (d[k] >> 12)) : -1;  // -1: no pass
        }
        for (int kp = 0; kp < NKP; kp++) {
#pragma unroll
            for (int k = 0; k < E_PER; k++) {
                if (key[k] == kp) {
                    int pos = atomicAdd(&cnt[d[k]], 1);
                    if (pos < SEG) csr[d[k] * SEG + pos] = s[k];  // clamp: P~0
                }
            }
        }
        return;
    }

    // ---- gemm role: h = x @ W1, 128 rows x 32 cols per block, K-tile 32 ----
    int g = bid / 3;
    int tc = t & 7;    // cols tc*4..tc*4+3
    int tr = t >> 3;   // rows tr*4..tr*4+3
    int base = g * 128;

    float4 acc[4] = {{0,0,0,0},{0,0,0,0},{0,0,0,0},{0,0,0,0}};
    int st_c4 = t & 7, st_row = t >> 3;

    for (int kt = 0; kt < IN_DIM; kt += 32) {
        __syncthreads();
#pragma unroll
        for (int i = 0; i < 4; i++) {
            int row = st_row + i * 32;
            int gr = min(base + row, NN - 1);
            float4 v = *(const float4*)(x + (size_t)gr * IN_DIM + kt + (st_c4 << 2));
            XsT[(st_c4 * 4 + 0) * XS_S + row] = v.x;
            XsT[(st_c4 * 4 + 1) * XS_S + row] = v.y;
            XsT[(st_c4 * 4 + 2) * XS_S + row] = v.z;
            XsT[(st_c4 * 4 + 3) * XS_S + row] = v.w;
        }
        *(float4*)&Ws[t * 4] = *(const float4*)(W + kt * HID + t * 4);
        __syncthreads();

#pragma unroll
        for (int kk = 0; kk < 32; kk++) {
            float4 xv = *(const float4*)&XsT[kk * XS_S + tr * 4];
            float4 wv = *(const float4*)&Ws[kk * HID + tc * 4];
            fma4(acc[0], xv.x, wv);
            fma4(acc[1], xv.y, wv);
            fma4(acc[2], xv.z, wv);
            fma4(acc[3], xv.w, wv);
        }
    }
#pragma unroll
    for (int r = 0; r < 4; r++) {
        int row = base + tr * 4 + r;
        if (row < NN) *(float4*)(h + (size_t)row * HID + (tc << 2)) = acc[r];
    }
}

// ---------------- scale: h1s[i] = h1[i] * dinv[i]; row NN zeroed ----------------
// R3: pre-scaling by dinv[src] makes both agg inner loops pure gather-sum.
// Row NN is an always-zero dummy row: pad lanes gather it harmlessly.
__global__ __launch_bounds__(256) void k_scale(const float* __restrict__ h1,
                                               const int* __restrict__ cnt,
                                               float* __restrict__ h1s) {
    int idx = blockIdx.x * 256 + threadIdx.x;  // (NN+1)*8 float4 slots
    if (idx >= (NN + 1) * 8) return;
    int row = idx >> 3, c4 = idx & 7;
    float4 v = {0.f, 0.f, 0.f, 0.f};
    if (row < NN) {
        float dn = rsqrtf((float)cnt[row] + 1.0f);
        float4 a = ((const float4*)(h1 + (size_t)row * HID))[c4];
        v.x = a.x * dn; v.y = a.y * dn; v.z = a.z * dn; v.w = a.w * dn;
    }
    ((float4*)(h1s + (size_t)row * HID))[c4] = v;
}

// ---------------- layer-1 aggregation: +b1, ReLU, BN -> h2s (pre-scaled) ----------
// half-wave per node, lanes = columns. Inner loop: shfl idx + row load + add
// (MLP=8). aggregate = dn_i * (sum_s h1s[s] + h1s[i]); output PRE-SCALED by
// dn_i so k_agg2 is also a pure gather-sum. Node n (==NN) writes dummy zeros.
__global__ __launch_bounds__(256) void k_agg1(const float* __restrict__ hs,
                                              const int* __restrict__ csr,
                                              const int* __restrict__ cnt,
                                              const float* __restrict__ bias,
                                              const float* __restrict__ gamma,
                                              const float* __restrict__ beta,
                                              const float* __restrict__ mean,
                                              const float* __restrict__ var,
                                              float* __restrict__ h2s, int n) {
    int t = threadIdx.x;
    int c = t & 31;
    int node = blockIdx.x * 8 + (t >> 5);
    if (node > n) return;
    if (node == n) {  // dummy zero row for agg2's pad gathers
        h2s[(size_t)n * HID + c] = 0.f;
        return;
    }

    int dnode = cnt[node];
    float dn = rsqrtf((float)dnode + 1.0f);
    int d = min(dnode, SEG);
    int o0 = node * SEG;
    float sum = hs[(size_t)node * HID + c];  // self term (already scaled by dn)

    for (int ch = 0; ch < d; ch += 32) {
        int rem = d - ch;
        int sv = (c < rem) ? csr[o0 + ch + c] : n;  // pad -> dummy zero row
        int m = min(rem, 32);
        int mu = (m + 7) & ~7;
        for (int j = 0; j < mu; j += 8) {
            int ss[8];
            float v[8];
#pragma unroll
            for (int u = 0; u < 8; u++) ss[u] = __shfl(sv, j + u, 32);
#pragma unroll
            for (int u = 0; u < 8; u++) v[u] = hs[(size_t)ss[u] * HID + c];
#pragma unroll
            for (int u = 0; u < 8; u++) sum += v[u];
        }
    }
    float acc = sum * dn;
    float v = fmaxf(acc + bias[c], 0.0f);  // + b1, ReLU
    v = (v - mean[c]) * rsqrtf(var[c] + BN_EPS) * gamma[c] + beta[c];
    h2s[(size_t)node * HID + c] = v * dn;  // pre-scaled for layer 2
}

// ---------------- layer-2: agg(h2s) then @W2 + b2, ReLU ----------------
// agg(h2@W2) = agg(h2)@W2 (scalar edge coefs). Pure gather-sum of pre-scaled
// rows, final *dn, then per-node 32x32 matvec epilogue.
__global__ __launch_bounds__(256) void k_agg2(const float* __restrict__ h2s,
                                              const int* __restrict__ csr,
                                              const int* __restrict__ cnt,
                                              const float* __restrict__ W2,
                                              const float* __restrict__ b2,
                                              float* __restrict__ out, int n) {
    __shared__ float W2s[32 * 32];
    int t = threadIdx.x;
    ((float4*)W2s)[t] = ((const float4*)W2)[t];  // 1024 floats exactly
    __syncthreads();

    int c = t & 31;
    int node = blockIdx.x * 8 + (t >> 5);
    if (node >= n) return;

    int dnode = cnt[node];
    float dn = rsqrtf((float)dnode + 1.0f);
    int d = min(dnode, SEG);
    int o0 = node * SEG;
    float sum = h2s[(size_t)node * HID + c];  // self term (already scaled)

    for (int ch = 0; ch < d; ch += 32) {
        int rem = d - ch;
        int sv = (c < rem) ? csr[o0 + ch + c] : n;  // pad -> dummy zero row
        int m = min(rem, 32);
        int mu = (m + 7) & ~7;
        for (int j = 0; j < mu; j += 8) {
            int ss[8];
            float v[8];
#pragma unroll
            for (int u = 0; u < 8; u++) ss[u] = __shfl(sv, j + u, 32);
#pragma unroll
            for (int u = 0; u < 8; u++) v[u] = h2s[(size_t)ss[u] * HID + c];
#pragma unroll
            for (int u = 0; u < 8; u++) sum += v[u];
        }
    }
    float acc = sum * dn;
    // matvec: out[c] = relu( sum_cc acc[cc] * W2[cc][c] + b2[c] )
    float g = 0.f;
#pragma unroll
    for (int cc = 0; cc < 32; cc++) {
        float a = __shfl(acc, cc, 32);
        g = fmaf(a, W2s[cc * HID + c], g);
    }
    out[(size_t)node * HID + c] = fmaxf(g + b2[c], 0.0f);
}

// ---------------- launch ----------------
extern "C" void kernel_launch(void* const* d_in, const int* in_sizes, int n_in,
                              void* d_out, int out_size, void* d_ws, size_t ws_size,
                              hipStream_t stream) {
    const float* x     = (const float*)d_in[0];
    const int*   ei    = (const int*)d_in[1];
    const int*   src   = ei;
    const int*   dst   = ei + NE;
    const float* W1    = (const float*)d_in[2];
    const float* b1    = (const float*)d_in[3];
    const float* W2    = (const float*)d_in[4];
    const float* b2    = (const float*)d_in[5];
    const float* gamma = (const float*)d_in[6];
    const float* beta  = (const float*)d_in[7];
    const float* rmean = (const float*)d_in[8];
    const float* rvar  = (const float*)d_in[9];
    float* out = (float*)d_out;

    char* ws = (char*)d_ws;
    int*   cnt = (int*)(ws);                          // 400 KB
    int*   csr = (int*)(ws + ((size_t)1 << 20));      // 25.6 MB (SEG=64)
    float* h1  = (float*)(ws + ((size_t)28 << 20));   // 12.8 MB
    float* h1s = (float*)(ws + ((size_t)42 << 20));   // 12.8 MB + dummy row NN
    float* h2s = (float*)(ws + ((size_t)56 << 20));   // 12.8 MB + dummy row NN

    k_zero<<<(NN + 255) / 256, 256, 0, stream>>>(cnt, NN);
    k_fill_gemm<<<FG_BLOCKS, 256, 0, stream>>>(src, dst, cnt, csr, x, W1, h1);
    k_scale<<<((NN + 1) * 8 + 255) / 256, 256, 0, stream>>>(h1, cnt, h1s);
    k_agg1<<<(NN + 1 + 7) / 8, 256, 0, stream>>>(h1s, csr, cnt, b1, gamma, beta,
                                                 rmean, rvar, h2s, NN);
    k_agg2<<<(NN + 7) / 8, 256, 0, stream>>>(h2s, csr, cnt, W2, b2, out, NN);
}

// Round 7
// 450.229 us; speedup vs baseline: 1.2481x; 1.2481x over previous
//
#include <hip/hip_runtime.h>
#include <hip/hip_fp16.h>

#define NN 100000
#define NE 1600000
#define IN_DIM 512
#define HID 32
#define BN_EPS 1e-5f

#define E_PER 4           // edges cached in registers per thread (fill role)
#define FILL_BLOCKS 1600  // 1600*256*4 = 1.6384M >= NE
#define GEMM_BLOCKS 782   // 782*128 = 100096 >= NN rows
#define FG_BLOCKS (FILL_BLOCKS + GEMM_BLOCKS)
#define NPASS 25          // dst ranges of 4096 nodes (R5 lesson: 325-pass src-sort
                          // cost +109us in fill and gained 0 in aggs -> reverted)
#define SEG 64            // fixed CSR slots per node; deg ~ Poisson(16), P(>=64) ~ 1e-19

// ---------------- utility ----------------
__global__ void k_zero(int* __restrict__ p, int n) {
    int i = blockIdx.x * 256 + threadIdx.x;
    if (i < n) p[i] = 0;
}

__device__ inline void fma4(float4& a, float s, const float4& w) {
    a.x = fmaf(s, w.x, a.x);
    a.y = fmaf(s, w.y, a.y);
    a.z = fmaf(s, w.z, a.z);
    a.w = fmaf(s, w.w, a.w);
}

// ---------------- fused CSR-fill + GEMM1 ----------------
// R2: fill (atomic/latency-bound) and gemm (HBM-BW-bound) are data-independent;
// block-interleaved 2:1 so both populations co-resident, stalls overlap.
// Exact R4 configuration (measured 161us, FETCH 107MB, WRITE 105MB).
#define XS_S 132
__global__ __launch_bounds__(256) void k_fill_gemm(const int* __restrict__ src,
                                                   const int* __restrict__ dst,
                                                   int* __restrict__ cnt,
                                                   int* __restrict__ csr,
                                                   const float* __restrict__ x,
                                                   const float* __restrict__ W,
                                                   float* __restrict__ h) {
    __shared__ float XsT[32 * XS_S];  // 16.9 KB (gemm role only)
    __shared__ float Ws[32 * 32];     // 4 KB
    int bid = blockIdx.x;
    int t = threadIdx.x;
    bool is_gemm = (bid % 3 == 2) && (bid / 3 < GEMM_BLOCKS);

    if (!is_gemm) {
        // ---- fill role ----
        int f = bid - min(GEMM_BLOCKS, (bid + 1) / 3);
        const int nthreads = FILL_BLOCKS * 256;
        int tid = f * 256 + t;
        int s[E_PER], d[E_PER];
#pragma unroll
        for (int k = 0; k < E_PER; k++) {
            int e = tid + k * nthreads;
            bool ok = (e < NE);
            s[k] = ok ? src[e] : 0;
            d[k] = ok ? dst[e] : -1;  // -1 >> 12 == -1: matches no pass
        }
        for (int p = 0; p < NPASS; p++) {
#pragma unroll
            for (int k = 0; k < E_PER; k++) {
                if ((d[k] >> 12) == p) {
                    int pos = atomicAdd(&cnt[d[k]], 1);
                    if (pos < SEG) csr[d[k] * SEG + pos] = s[k];  // clamp: P~0
                }
            }
        }
        return;
    }

    // ---- gemm role: h = x @ W1, 128 rows x 32 cols per block, K-tile 32 ----
    int g = bid / 3;
    int tc = t & 7;    // cols tc*4..tc*4+3
    int tr = t >> 3;   // rows tr*4..tr*4+3
    int base = g * 128;

    float4 acc[4] = {{0,0,0,0},{0,0,0,0},{0,0,0,0},{0,0,0,0}};
    int st_c4 = t & 7, st_row = t >> 3;

    for (int kt = 0; kt < IN_DIM; kt += 32) {
        __syncthreads();
#pragma unroll
        for (int i = 0; i < 4; i++) {
            int row = st_row + i * 32;
            int gr = min(base + row, NN - 1);
            float4 v = *(const float4*)(x + (size_t)gr * IN_DIM + kt + (st_c4 << 2));
            XsT[(st_c4 * 4 + 0) * XS_S + row] = v.x;
            XsT[(st_c4 * 4 + 1) * XS_S + row] = v.y;
            XsT[(st_c4 * 4 + 2) * XS_S + row] = v.z;
            XsT[(st_c4 * 4 + 3) * XS_S + row] = v.w;
        }
        *(float4*)&Ws[t * 4] = *(const float4*)(W + kt * HID + t * 4);
        __syncthreads();

#pragma unroll
        for (int kk = 0; kk < 32; kk++) {
            float4 xv = *(const float4*)&XsT[kk * XS_S + tr * 4];
            float4 wv = *(const float4*)&Ws[kk * HID + tc * 4];
            fma4(acc[0], xv.x, wv);
            fma4(acc[1], xv.y, wv);
            fma4(acc[2], xv.z, wv);
            fma4(acc[3], xv.w, wv);
        }
    }
#pragma unroll
    for (int r = 0; r < 4; r++) {
        int row = base + tr * 4 + r;
        if (row < NN) *(float4*)(h + (size_t)row * HID + (tc << 2)) = acc[r];
    }
}

// ---------------- scale: h1s16[i] = fp16(h1[i] * dinv[i]); row NN zeroed --------
// R6: gather table in fp16. Aggs are L3 random-line-fetch bound (~2.5 TB/s,
// R3/R4 post-mortems); fp16 rows halve gather bytes AND pack 2 rows per 128-B
// line -> L3 line traffic halves again, table (6.4 MB) nearly L2-resident.
// Accumulation/self-terms/outputs stay fp32.
__global__ __launch_bounds__(256) void k_scale(const float* __restrict__ h1,
                                               const int* __restrict__ cnt,
                                               __half* __restrict__ h1s16) {
    int idx = blockIdx.x * 256 + threadIdx.x;  // (NN+1)*4 groups of 8 cols
    if (idx >= (NN + 1) * 4) return;
    int row = idx >> 2, c8 = (idx & 3) * 8;
    float dn = 0.f;
    float4 a = {0,0,0,0}, b = {0,0,0,0};
    if (row < NN) {
        dn = rsqrtf((float)cnt[row] + 1.0f);
        a = *(const float4*)(h1 + (size_t)row * HID + c8);
        b = *(const float4*)(h1 + (size_t)row * HID + c8 + 4);
    }
    __half2 p0 = __floats2half2_rn(a.x * dn, a.y * dn);
    __half2 p1 = __floats2half2_rn(a.z * dn, a.w * dn);
    __half2 p2 = __floats2half2_rn(b.x * dn, b.y * dn);
    __half2 p3 = __floats2half2_rn(b.z * dn, b.w * dn);
    uint4 o;
    o.x = *(unsigned int*)&p0;
    o.y = *(unsigned int*)&p1;
    o.z = *(unsigned int*)&p2;
    o.w = *(unsigned int*)&p3;
    *(uint4*)(h1s16 + (size_t)row * HID + c8) = o;
}

// ---------------- layer-1 aggregation: +b1, ReLU, BN -> h2s32/h2s16 ------------
// half-wave per node, lanes = columns. Inner loop: shfl idx + fp16 row load +
// fp32 add (MLP=8). Self term from fp32 h1 (exact). Output written twice:
// fp32 (agg2 self term) and fp16 (agg2 gather table). Node n: dummy zeros.
__global__ __launch_bounds__(256) void k_agg1(const float* __restrict__ h1,
                                              const __half* __restrict__ hs16,
                                              const int* __restrict__ csr,
                                              const int* __restrict__ cnt,
                                              const float* __restrict__ bias,
                                              const float* __restrict__ gamma,
                                              const float* __restrict__ beta,
                                              const float* __restrict__ mean,
                                              const float* __restrict__ var,
                                              float* __restrict__ h2s32,
                                              __half* __restrict__ h2s16, int n) {
    int t = threadIdx.x;
    int c = t & 31;
    int node = blockIdx.x * 8 + (t >> 5);
    if (node > n) return;
    if (node == n) {  // dummy zero row for agg2's pad gathers
        h2s32[(size_t)n * HID + c] = 0.f;
        h2s16[(size_t)n * HID + c] = __float2half(0.f);
        return;
    }

    int dnode = cnt[node];
    float dn = rsqrtf((float)dnode + 1.0f);
    int d = min(dnode, SEG);
    int o0 = node * SEG;
    float sum = h1[(size_t)node * HID + c] * dn;  // self term fp32 (x dn again at end)

    for (int ch = 0; ch < d; ch += 32) {
        int rem = d - ch;
        int sv = (c < rem) ? csr[o0 + ch + c] : n;  // pad -> dummy zero row
        int m = min(rem, 32);
        int mu = (m + 7) & ~7;
        for (int j = 0; j < mu; j += 8) {
            int ss[8];
            float v[8];
#pragma unroll
            for (int u = 0; u < 8; u++) ss[u] = __shfl(sv, j + u, 32);
#pragma unroll
            for (int u = 0; u < 8; u++) v[u] = __half2float(hs16[(size_t)ss[u] * HID + c]);
#pragma unroll
            for (int u = 0; u < 8; u++) sum += v[u];
        }
    }
    float acc = sum * dn;
    float v = fmaxf(acc + bias[c], 0.0f);  // + b1, ReLU
    v = (v - mean[c]) * rsqrtf(var[c] + BN_EPS) * gamma[c] + beta[c];
    float vs = v * dn;                     // pre-scaled for layer 2
    h2s32[(size_t)node * HID + c] = vs;
    h2s16[(size_t)node * HID + c] = __float2half(vs);
}

// ---------------- layer-2: agg(h2s) then @W2 + b2, ReLU ----------------
// agg(h2@W2) = agg(h2)@W2 (scalar edge coefs). fp16 gather-sum of pre-scaled
// rows (self from fp32 copy), final *dn, then per-node 32x32 matvec epilogue.
__global__ __launch_bounds__(256) void k_agg2(const float* __restrict__ h2s32,
                                              const __half* __restrict__ h2s16,
                                              const int* __restrict__ csr,
                                              const int* __restrict__ cnt,
                                              const float* __restrict__ W2,
                                              const float* __restrict__ b2,
                                              float* __restrict__ out, int n) {
    __shared__ float W2s[32 * 32];
    int t = threadIdx.x;
    ((float4*)W2s)[t] = ((const float4*)W2)[t];  // 1024 floats exactly
    __syncthreads();

    int c = t & 31;
    int node = blockIdx.x * 8 + (t >> 5);
    if (node >= n) return;

    int dnode = cnt[node];
    float dn = rsqrtf((float)dnode + 1.0f);
    int d = min(dnode, SEG);
    int o0 = node * SEG;
    float sum = h2s32[(size_t)node * HID + c];  // self term fp32 (already scaled)

    for (int ch = 0; ch < d; ch += 32) {
        int rem = d - ch;
        int sv = (c < rem) ? csr[o0 + ch + c] : n;  // pad -> dummy zero row
        int m = min(rem, 32);
        int mu = (m + 7) & ~7;
        for (int j = 0; j < mu; j += 8) {
            int ss[8];
            float v[8];
#pragma unroll
            for (int u = 0; u < 8; u++) ss[u] = __shfl(sv, j + u, 32);
#pragma unroll
            for (int u = 0; u < 8; u++) v[u] = __half2float(h2s16[(size_t)ss[u] * HID + c]);
#pragma unroll
            for (int u = 0; u < 8; u++) sum += v[u];
        }
    }
    float acc = sum * dn;
    // matvec: out[c] = relu( sum_cc acc[cc] * W2[cc][c] + b2[c] )
    float g = 0.f;
#pragma unroll
    for (int cc = 0; cc < 32; cc++) {
        float a = __shfl(acc, cc, 32);
        g = fmaf(a, W2s[cc * HID + c], g);
    }
    out[(size_t)node * HID + c] = fmaxf(g + b2[c], 0.0f);
}

// ---------------- launch ----------------
extern "C" void kernel_launch(void* const* d_in, const int* in_sizes, int n_in,
                              void* d_out, int out_size, void* d_ws, size_t ws_size,
                              hipStream_t stream) {
    const float* x     = (const float*)d_in[0];
    const int*   ei    = (const int*)d_in[1];
    const int*   src   = ei;
    const int*   dst   = ei + NE;
    const float* W1    = (const float*)d_in[2];
    const float* b1    = (const float*)d_in[3];
    const float* W2    = (const float*)d_in[4];
    const float* b2    = (const float*)d_in[5];
    const float* gamma = (const float*)d_in[6];
    const float* beta  = (const float*)d_in[7];
    const float* rmean = (const float*)d_in[8];
    const float* rvar  = (const float*)d_in[9];
    float* out = (float*)d_out;

    char* ws = (char*)d_ws;
    int*    cnt   = (int*)(ws);                        // 400 KB
    int*    csr   = (int*)(ws + ((size_t)1 << 20));    // 25.6 MB (SEG=64)
    float*  h1    = (float*)(ws + ((size_t)28 << 20)); // 12.8 MB
    __half* h1s16 = (__half*)(ws + ((size_t)42 << 20));// 6.4 MB + dummy row NN
    float*  h2s32 = (float*)(ws + ((size_t)50 << 20)); // 12.8 MB + dummy row NN
    __half* h2s16 = (__half*)(ws + ((size_t)64 << 20));// 6.4 MB + dummy row NN

    k_zero<<<(NN + 255) / 256, 256, 0, stream>>>(cnt, NN);
    k_fill_gemm<<<FG_BLOCKS, 256, 0, stream>>>(src, dst, cnt, csr, x, W1, h1);
    k_scale<<<((NN + 1) * 4 + 255) / 256, 256, 0, stream>>>(h1, cnt, h1s16);
    k_agg1<<<(NN + 1 + 7) / 8, 256, 0, stream>>>(h1, h1s16, csr, cnt, b1, gamma,
                                                 beta, rmean, rvar, h2s32, h2s16, NN);
    k_agg2<<<(NN + 7) / 8, 256, 0, stream>>>(h2s32, h2s16, csr, cnt, W2, b2, out, NN);
}